// Round 7
// baseline (142.414 us; speedup 1.0000x reference)
//
#include <hip/hip_runtime.h>
#include <hip/hip_bf16.h>
#include <stdint.h>

// Problem shape (fixed by reference)
#define B_ 32
#define T_ 1024
#define J_ 256
#define D_ 512

typedef __attribute__((ext_vector_type(8))) short short8;   // 8 bf16 (4 VGPRs)
typedef __attribute__((ext_vector_type(4))) float floatx4;  // MFMA C/D frag

// ---------------------------------------------------------------------------
// Kernel 1: prep_u — tu[j] = sum_k u[j,k]*w_u[k]  and  B2f = bf16(u*w_m + w_h)
// written in MFMA B-FRAGMENT ORDER:
//   value for (j, k)  [j = n*16+fr, k = ks*32 + kq*8 + e, e<8]  stored at
//   B2f[ ((b*16 + n)*16 + ks)*512 + (kq*16 + fr)*8 + e ]
// so a gemm wave's B-fragment load for (n,ks) is base + lane*8 — one
// perfectly coalesced 1 KB global_load_dwordx4 per fragment, no LDS needed.
// prep lane covers k = lane*8..+8  ->  ks = lane>>2, kq = lane&3: the lane's
// 8 values form exactly one 16 B fragment chunk.
// ---------------------------------------------------------------------------
__global__ __launch_bounds__(256) void prep_u_kernel(
    const float* __restrict__ u, const float* __restrict__ w,
    __hip_bfloat16* __restrict__ B2f, float* __restrict__ tu)
{
    int row  = blockIdx.x * 4 + (threadIdx.x >> 6);   // one wave per u-row
    int lane = threadIdx.x & 63;
    const float* src = u + (size_t)row * D_;
    int base = lane * 8;

    float4 v0  = *(const float4*)(src + base);
    float4 v1  = *(const float4*)(src + base + 4);
    float4 wh0 = *(const float4*)(w + base);            // w_h = w[0:512]
    float4 wh1 = *(const float4*)(w + base + 4);
    float4 wu0 = *(const float4*)(w + D_ + base);       // w_u = w[512:1024]
    float4 wu1 = *(const float4*)(w + D_ + base + 4);
    float4 wm0 = *(const float4*)(w + 2*D_ + base);     // w_m = w[1024:1536]
    float4 wm1 = *(const float4*)(w + 2*D_ + base + 4);

    float s = v0.x*wu0.x + v0.y*wu0.y + v0.z*wu0.z + v0.w*wu0.w
            + v1.x*wu1.x + v1.y*wu1.y + v1.z*wu1.z + v1.w*wu1.w;

    float vals[8] = {
        v0.x*wm0.x + wh0.x, v0.y*wm0.y + wh0.y,
        v0.z*wm0.z + wh0.z, v0.w*wm0.w + wh0.w,
        v1.x*wm1.x + wh1.x, v1.y*wm1.y + wh1.y,
        v1.z*wm1.z + wh1.z, v1.w*wm1.w + wh1.w };

    union { __hip_bfloat16 b[8]; uint4 q; } pk;
#pragma unroll
    for (int i = 0; i < 8; i++) pk.b[i] = __float2bfloat16(vals[i]);

    // scatter 16 B chunk into fragment layout
    int b  = row >> 8;          // J_ = 256
    int j  = row & 255;
    int n  = j >> 4, fr = j & 15;
    int ks = lane >> 2, kq = lane & 3;
    size_t dst = ((((size_t)b * 16 + n) * 16 + ks) * 512) + (kq * 16 + fr) * 8;
    *(uint4*)(B2f + dst) = pk.q;

#pragma unroll
    for (int off = 32; off > 0; off >>= 1) s += __shfl_down(s, off, 64);
    if (lane == 0) tu[row] = s;
}

// ---------------------------------------------------------------------------
// Kernel 2: fused GEMM  out[b] = bf16(h[b]) @ B2^T + tu
//
// Round-7: ZERO LDS, ZERO barriers (R2-R6 all plateaued at 37-48 us because
// __syncthreads' vmcnt(0) drains prefetch DMAs — structural, per m131-m141).
//  - 256 threads = 4 waves; wave w owns rows w*32..+32 (2 m-tiles) x 128
//    cols (8 n-tiles). Block tile 128x128; grid 512 = 2 blocks/CU.
//  - Per k-step: 8 coalesced B-fragment loads (bf16, L2-hot: 256 KB/batch)
//    + 4 A float4 loads (h fp32, cvt->bf16 in regs) + 16 MFMA.
//  - Manual 1-deep software pipeline: loads for ks+1 issue before MFMAs of
//    ks — compiler emits fine-grained vmcnt(N), never a full drain.
// ---------------------------------------------------------------------------
__global__ __launch_bounds__(256, 2) void gemm_kernel(
    const float* __restrict__ h,             // [B, T, D] fp32
    const __hip_bfloat16* __restrict__ B2f,  // fragment-ordered, see prep
    const float* __restrict__ tu,            // [B*J] fp32
    float* __restrict__ out)                 // [B, T, J] fp32
{
    const int b   = blockIdx.y;
    const int tM  = blockIdx.x >> 1;        // T/128 = 8
    const int tN  = blockIdx.x & 1;         // J/128 = 2
    const int tid = threadIdx.x;
    const int w = tid >> 6, lane = tid & 63;
    const int fr = lane & 15;               // n (col) within 16-tile
    const int kq = lane >> 4;               // k-quarter 0..3

    // A: lane reads rows (m-tiles) tM*128 + w*32 + {0,16} + fr
    const float* A0 = h + ((size_t)b * T_ + tM * 128 + w * 32 + fr) * D_ + kq * 8;
    const float* A1 = A0 + 16 * D_;
    // B fragments: block (n,ks) at Bf + (n*16+ks)*512, lane-linear
    const __hip_bfloat16* Bf =
        B2f + (((size_t)b * 16 + tN * 8) * 16) * 512 + lane * 8;

    floatx4 acc[2][8];
#pragma unroll
    for (int mi = 0; mi < 2; mi++)
#pragma unroll
        for (int n = 0; n < 8; n++) acc[mi][n] = (floatx4)0.0f;

    short8 bC[8], bN[8];
    float4 aC[2][2], aN[2][2];

    // prologue: load k-step 0
#pragma unroll
    for (int n = 0; n < 8; n++)
        bC[n] = *(const short8*)(Bf + (n * 16 + 0) * 512);
    aC[0][0] = *(const float4*)(A0);      aC[0][1] = *(const float4*)(A0 + 4);
    aC[1][0] = *(const float4*)(A1);      aC[1][1] = *(const float4*)(A1 + 4);

#pragma unroll
    for (int ks = 0; ks < 16; ks++) {
        // issue next step's loads before this step's MFMAs
        if (ks < 15) {
#pragma unroll
            for (int n = 0; n < 8; n++)
                bN[n] = *(const short8*)(Bf + (n * 16 + ks + 1) * 512);
            const float* p0 = A0 + (ks + 1) * 32;
            const float* p1 = A1 + (ks + 1) * 32;
            aN[0][0] = *(const float4*)(p0); aN[0][1] = *(const float4*)(p0 + 4);
            aN[1][0] = *(const float4*)(p1); aN[1][1] = *(const float4*)(p1 + 4);
        }

        // cvt current A raw -> bf16 frags
        short8 af[2];
#pragma unroll
        for (int mi = 0; mi < 2; mi++) {
            union { __hip_bfloat16 e[8]; short8 v; } pk;
            pk.e[0]=__float2bfloat16(aC[mi][0].x); pk.e[1]=__float2bfloat16(aC[mi][0].y);
            pk.e[2]=__float2bfloat16(aC[mi][0].z); pk.e[3]=__float2bfloat16(aC[mi][0].w);
            pk.e[4]=__float2bfloat16(aC[mi][1].x); pk.e[5]=__float2bfloat16(aC[mi][1].y);
            pk.e[6]=__float2bfloat16(aC[mi][1].z); pk.e[7]=__float2bfloat16(aC[mi][1].w);
            af[mi] = pk.v;
        }

#pragma unroll
        for (int mi = 0; mi < 2; mi++)
#pragma unroll
            for (int n = 0; n < 8; n++)
                acc[mi][n] = __builtin_amdgcn_mfma_f32_16x16x32_bf16(
                    af[mi], bC[n], acc[mi][n], 0, 0, 0);

        if (ks < 15) {
#pragma unroll
            for (int n = 0; n < 8; n++) bC[n] = bN[n];
#pragma unroll
            for (int mi = 0; mi < 2; mi++) {
                aC[mi][0] = aN[mi][0]; aC[mi][1] = aN[mi][1];
            }
        }
    }

    // epilogue: C/D layout col = lane&15, row = (lane>>4)*4 + reg  [m89/m91]
    const size_t outB = (size_t)b * T_ * J_;
    const float* tub = tu + b * J_;
#pragma unroll
    for (int mi = 0; mi < 2; mi++) {
        int r0 = tM * 128 + w * 32 + mi * 16 + kq * 4;
#pragma unroll
        for (int n = 0; n < 8; n++) {
            int col = tN * 128 + n * 16 + fr;
            float tuv = tub[col];
#pragma unroll
            for (int r = 0; r < 4; r++) {
                out[outB + (size_t)(r0 + r) * J_ + col] = acc[mi][n][r] + tuv;
            }
        }
    }
}

// ---------------------------------------------------------------------------
extern "C" void kernel_launch(void* const* d_in, const int* in_sizes, int n_in,
                              void* d_out, int out_size, void* d_ws, size_t ws_size,
                              hipStream_t stream)
{
    const float* h = (const float*)d_in[0];
    const float* u = (const float*)d_in[1];
    const float* w = (const float*)d_in[2];
    float* out = (float*)d_out;

    uint8_t* ws = (uint8_t*)d_ws;
    __hip_bfloat16* B2f = (__hip_bfloat16*)ws;                // 8 MiB (frag order)
    float* tu = (float*)(ws + (size_t)B_ * J_ * D_ * 2);      // 32 KiB

    // one wave per u-row; 4 rows per 256-thread block; 8192 rows total
    prep_u_kernel<<<dim3(B_ * J_ / 4), 256, 0, stream>>>(u, w, B2f, tu);

    // 128x128 tiles: 8 tM x 2 tN x 32 batches = 512 blocks, no LDS/barriers
    gemm_kernel<<<dim3((T_ / 128) * (J_ / 128), B_), 256, 0, stream>>>(h, B2f, tu, out);
}

// Round 8
// 127.685 us; speedup vs baseline: 1.1154x; 1.1154x over previous
//
#include <hip/hip_runtime.h>
#include <hip/hip_bf16.h>
#include <stdint.h>

// Problem shape (fixed by reference)
#define B_ 32
#define T_ 1024
#define J_ 256
#define D_ 512

typedef __attribute__((ext_vector_type(8))) short short8;   // 8 bf16 (4 VGPRs)
typedef __attribute__((ext_vector_type(4))) float floatx4;  // MFMA C/D frag

// ---------------------------------------------------------------------------
// Kernel 1: prep_u — B2[j,k] = bf16(u[j,k]*w_m[k] + w_h[k]),
//                    tu[j]   = sum_k u[j,k]*w_u[k]   (fp32)
// Identity: out[t,j] = sum_k h[t,k]*B2[j,k] + tu[j]
// ---------------------------------------------------------------------------
__global__ __launch_bounds__(256) void prep_u_kernel(
    const float* __restrict__ u, const float* __restrict__ w,
    __hip_bfloat16* __restrict__ B2, float* __restrict__ tu)
{
    int row  = blockIdx.x * 4 + (threadIdx.x >> 6);   // one wave per u-row
    int lane = threadIdx.x & 63;
    const float* src = u + (size_t)row * D_;
    int base = lane * 8;

    float4 v0  = *(const float4*)(src + base);
    float4 v1  = *(const float4*)(src + base + 4);
    float4 wh0 = *(const float4*)(w + base);            // w_h = w[0:512]
    float4 wh1 = *(const float4*)(w + base + 4);
    float4 wu0 = *(const float4*)(w + D_ + base);       // w_u = w[512:1024]
    float4 wu1 = *(const float4*)(w + D_ + base + 4);
    float4 wm0 = *(const float4*)(w + 2*D_ + base);     // w_m = w[1024:1536]
    float4 wm1 = *(const float4*)(w + 2*D_ + base + 4);

    float s = v0.x*wu0.x + v0.y*wu0.y + v0.z*wu0.z + v0.w*wu0.w
            + v1.x*wu1.x + v1.y*wu1.y + v1.z*wu1.z + v1.w*wu1.w;

    float vals[8] = {
        v0.x*wm0.x + wh0.x, v0.y*wm0.y + wh0.y,
        v0.z*wm0.z + wh0.z, v0.w*wm0.w + wh0.w,
        v1.x*wm1.x + wh1.x, v1.y*wm1.y + wh1.y,
        v1.z*wm1.z + wh1.z, v1.w*wm1.w + wh1.w };

    union { __hip_bfloat16 b[8]; uint4 q; } pk;
#pragma unroll
    for (int i = 0; i < 8; i++) pk.b[i] = __float2bfloat16(vals[i]);
    *(uint4*)(B2 + (size_t)row * D_ + base) = pk.q;     // 16B coalesced store

#pragma unroll
    for (int off = 32; off > 0; off >>= 1) s += __shfl_down(s, off, 64);
    if (lane == 0) tu[row] = s;
}

// ---------------------------------------------------------------------------
// Kernel 2: fused GEMM  out[b] = bf16(h[b]) @ B2[b]^T + tu
//
// Round-8 = Round-5 (best: h read EXACTLY once, full-J tile) + two fixes:
//  (a) grid dims swapped (x = batch, y = tM): linear id = b + 32*tM, so all
//      8 tM-blocks of batch b land on XCD b%8 -> B2[b] (512 KB) L2-resident,
//      its 8x re-read served by L2 not L3.  [R5 spread them over all XCDs]
//  (b) explicit 1-step A register prefetch across the WHOLE K-loop (A loads
//      are global, independent of LDS phases/barriers). R5's VGPR=44 proved
//      the compiler sank A loads to point-of-use = dependent-serial.
//  - 128x256 tile, 1024 thr (16 waves, 8x2), 256 blocks = 1/CU.
//  - B2 staged async (global_load_lds), 4 phases of K=128, double-buffered.
// ---------------------------------------------------------------------------
__device__ inline void gload_lds16(const void* g, void* l) {
    __builtin_amdgcn_global_load_lds(
        (__attribute__((address_space(1))) void*)(g),
        (__attribute__((address_space(3))) void*)(l),
        16, 0, 0);
}

__global__ __launch_bounds__(1024, 4) void gemm_kernel(
    const float* __restrict__ h,            // [B, T, D] fp32
    const __hip_bfloat16* __restrict__ B2,  // [B, J, D] bf16 (= u*w_m + w_h)
    const float* __restrict__ tu,           // [B*J] fp32
    float* __restrict__ out)                // [B, T, J] fp32
{
    __shared__ __align__(16) __hip_bfloat16 sB[2][256 * 128];  // 2 x 64 KB

    const int b   = blockIdx.x;             // batch -> XCD b%8 (locality)
    const int tM  = blockIdx.y;             // T/128 = 8 tiles
    const int tid = threadIdx.x;
    const int w = tid >> 6, lane = tid & 63;
    const int wr = w >> 1, wc = w & 1;      // 8x2 wave grid

    const int fr = lane & 15;               // row within 16-tile (m or n)
    const int kq = lane >> 4;               // k-quarter 0..3

    // this wave's 16 A-rows; lane reads row fr, k-slice kq*8
    const float* Aw = h + ((size_t)b * T_ + tM * 128 + wr * 16 + fr) * D_ + kq * 8;
    const __hip_bfloat16* Bb = B2 + (size_t)b * J_ * D_;

    floatx4 acc[8];
#pragma unroll
    for (int n = 0; n < 8; n++) acc[n] = (floatx4)0.0f;

    // ---- stage phase 0 into buffer 0 (4096 chunks, 4 per thread)
#pragma unroll
    for (int i = 0; i < 4; i++) {
        int q = i * 1024 + tid;             // lane-linear LDS chunk
        int j = q >> 4;
        int c = (q & 15) ^ (j & 15);        // source k-chunk (XOR swizzle)
        gload_lds16(Bb + (size_t)j * D_ + c * 8, &sB[0][q * 8]);
    }

    // ---- A prefetch pipeline: aC = k-step 0 (issued before the barrier,
    // overlaps the phase-0 DMA drain)
    float4 aC0 = *(const float4*)(Aw);
    float4 aC1 = *(const float4*)(Aw + 4);
    float4 aN0, aN1;
    __syncthreads();

    for (int p = 0; p < 4; p++) {
        // ---- async prefetch of phase p+1 into the other buffer
        if (p < 3) {
#pragma unroll
            for (int i = 0; i < 4; i++) {
                int q = i * 1024 + tid;
                int j = q >> 4;
                int c = (q & 15) ^ (j & 15);
                gload_lds16(Bb + (size_t)j * D_ + (p + 1) * 128 + c * 8,
                            &sB[(p + 1) & 1][q * 8]);
            }
        }
        const __hip_bfloat16* sBp = sB[p & 1];

        // ---- 4 k-steps; A loads run one step ahead (global, no barriers)
#pragma unroll
        for (int ks = 0; ks < 4; ks++) {
            int ki = p * 4 + ks;
            if (ki < 15) {                  // issue NEXT A load now
                const float* ap = Aw + (ki + 1) * 32;
                aN0 = *(const float4*)(ap);
                aN1 = *(const float4*)(ap + 4);
            }
            union { __hip_bfloat16 e[8]; short8 v; } af;
            af.e[0]=__float2bfloat16(aC0.x); af.e[1]=__float2bfloat16(aC0.y);
            af.e[2]=__float2bfloat16(aC0.z); af.e[3]=__float2bfloat16(aC0.w);
            af.e[4]=__float2bfloat16(aC1.x); af.e[5]=__float2bfloat16(aC1.y);
            af.e[6]=__float2bfloat16(aC1.z); af.e[7]=__float2bfloat16(aC1.w);
#pragma unroll
            for (int n = 0; n < 8; n++) {
                int j = wc * 128 + n * 16 + fr;
                int c = ks * 4 + kq;
                short8 bf = *(const short8*)(sBp + (j * 16 + (c ^ (j & 15))) * 8);
                acc[n] = __builtin_amdgcn_mfma_f32_16x16x32_bf16(
                    af.v, bf, acc[n], 0, 0, 0);
            }
            if (ki < 15) { aC0 = aN0; aC1 = aN1; }
        }
        __syncthreads();   // phase handoff (DMAs aged a full phase)
    }

    // epilogue: C/D layout col = lane&15, row = (lane>>4)*4 + reg  [m89/m91]
    const size_t outB = (size_t)b * T_ * J_;
    const int r0 = tM * 128 + wr * 16 + kq * 4;
    const float* tub = tu + b * J_;
#pragma unroll
    for (int n = 0; n < 8; n++) {
        int col = wc * 128 + n * 16 + fr;
        float tuv = tub[col];
#pragma unroll
        for (int r = 0; r < 4; r++) {
            out[outB + (size_t)(r0 + r) * J_ + col] = acc[n][r] + tuv;
        }
    }
}

// ---------------------------------------------------------------------------
extern "C" void kernel_launch(void* const* d_in, const int* in_sizes, int n_in,
                              void* d_out, int out_size, void* d_ws, size_t ws_size,
                              hipStream_t stream)
{
    const float* h = (const float*)d_in[0];
    const float* u = (const float*)d_in[1];
    const float* w = (const float*)d_in[2];
    float* out = (float*)d_out;

    uint8_t* ws = (uint8_t*)d_ws;
    __hip_bfloat16* B2 = (__hip_bfloat16*)ws;                 // 8 MiB
    float* tu = (float*)(ws + (size_t)B_ * J_ * D_ * 2);      // 32 KiB

    // one wave per u-row; 4 rows per 256-thread block; 8192 rows total
    prep_u_kernel<<<dim3(B_ * J_ / 4), 256, 0, stream>>>(u, w, B2, tu);

    // 128x256 tiles (full J): x = batch (XCD locality), y = tM
    gemm_kernel<<<dim3(B_, T_ / 128), 1024, 0, stream>>>(h, B2, tu, out);
}